// Round 3
// baseline (429.533 us; speedup 1.0000x reference)
//
#include <hip/hip_runtime.h>
#include <math.h>

#define NF   128   // n_features
#define DE   64    // d_embed
#define GS   5     // grid_size
#define SO   3     // spline_order
#define FG   10    // fourier_gridsize
#define NG   12    // grid cols = GS + 2*SO + 1
#define NB0  11    // order-0 bases
#define NBF  8     // final bases = GS + SO
#define WREC 32    // packed floats per (n,d) record
// packed W[(n*64+d)*32]: [0]=base_w, [1]=fourier_bias, [2..9]=spline_w*scaler,
//                        [10..19]=c_cos, [20..29]=c_sin, [30,31]=pad
// INV[n*32 + j]: j 0..10 = 1/(g[j+1]-g[j]); 11..20 = 1/(g[j+2]-g[j]); 21..29 = 1/(g[j+3]-g[j])

__global__ __launch_bounds__(256)
void kan_prep(const float* __restrict__ grid,
              const float* __restrict__ bw, const float* __restrict__ sw,
              const float* __restrict__ ss, const float* __restrict__ fc,
              const float* __restrict__ fb,
              float* __restrict__ W, float* __restrict__ INV) {
  int idx = blockIdx.x * blockDim.x + threadIdx.x;
  if (idx >= NF * DE) return;
  int n = idx >> 6, d = idx & 63;
  (void)d;
  float* w = W + (size_t)idx * WREC;
  w[0] = bw[idx];
  w[1] = fb[idx];
  float s = ss[idx];
  const float* swp = sw + (size_t)idx * NBF;
#pragma unroll
  for (int i = 0; i < NBF; ++i) w[2 + i] = swp[i] * s;
  const float* f0 = fc + (size_t)idx * FG;
  const float* f1 = fc + (size_t)(NF * DE + idx) * FG;
#pragma unroll
  for (int g = 0; g < FG; ++g) { w[10 + g] = f0[g]; w[20 + g] = f1[g]; }
  w[30] = 0.f; w[31] = 0.f;
  if (d == 0) {
    const float* g_ = grid + n * NG;
    float* iv = INV + n * 32;
    int o = 0;
#pragma unroll
    for (int k = 1; k <= SO; ++k)
      for (int j = 0; j + k < NG; ++j)
        iv[o++] = 1.0f / (g_[j + k] - g_[j]);
    iv[30] = 0.f; iv[31] = 0.f;
  }
}

template <bool PACKED>
__global__ __launch_bounds__(256)
void kan_main(const float* __restrict__ x, const float* __restrict__ grid,
              const float* __restrict__ bw, const float* __restrict__ sw,
              const float* __restrict__ ss, const float* __restrict__ fc,
              const float* __restrict__ fb,
              const float* __restrict__ W, const float* __restrict__ INV,
              float* __restrict__ out, int B) {
  const int n = blockIdx.x;
  const int wv = threadIdx.x >> 6;
  const int lane = threadIdx.x & 63;
  const int b = ((blockIdx.y * 4 + wv) << 6) + lane;
  if (b >= B) return;

  const float xv = x[(size_t)b * NF + n];

  float g[NG];
#pragma unroll
  for (int j = 0; j < NG; ++j) g[j] = grid[n * NG + j];

  // SiLU
  const float sil = xv / (1.0f + expf(-xv));

  // Cox-de Boor B-spline bases (order 0 -> 3)
  float bs[NB0];
#pragma unroll
  for (int j = 0; j < NB0; ++j)
    bs[j] = (xv >= g[j] && xv < g[j + 1]) ? 1.0f : 0.0f;

  if (PACKED) {
    const float* iv = INV + n * 32;
    const float* iv1 = iv;        // 11 entries
    const float* iv2 = iv + 11;   // 10 entries
    const float* iv3 = iv + 21;   // 9 entries
#pragma unroll
    for (int j = 0; j < 10; ++j) {
      float left  = (xv - g[j]) * iv1[j];
      float right = (g[j + 2] - xv) * iv1[j + 1];
      bs[j] = left * bs[j] + right * bs[j + 1];
    }
#pragma unroll
    for (int j = 0; j < 9; ++j) {
      float left  = (xv - g[j]) * iv2[j];
      float right = (g[j + 3] - xv) * iv2[j + 1];
      bs[j] = left * bs[j] + right * bs[j + 1];
    }
#pragma unroll
    for (int j = 0; j < 8; ++j) {
      float left  = (xv - g[j]) * iv3[j];
      float right = (g[j + 4] - xv) * iv3[j + 1];
      bs[j] = left * bs[j] + right * bs[j + 1];
    }
  } else {
#pragma unroll
    for (int k = 1; k <= SO; ++k) {
      for (int j = 0; j < NB0 - k; ++j) {
        float left  = (xv - g[j]) / (g[j + k] - g[j]);
        float right = (g[j + k + 1] - xv) / (g[j + k + 1] - g[j + 1]);
        bs[j] = left * bs[j] + right * bs[j + 1];
      }
    }
  }

  // Fourier harmonics: one precise sincos + angle-addition recurrence
  float cs[FG], sn[FG];
  float s1, c1;
  sincosf(xv, &s1, &c1);
  cs[0] = c1; sn[0] = s1;
#pragma unroll
  for (int gi = 1; gi < FG; ++gi) {
    float cp = cs[gi - 1], sp = sn[gi - 1];
    cs[gi] = cp * c1 - sp * s1;
    sn[gi] = sp * c1 + cp * s1;
  }

  float4* outp = reinterpret_cast<float4*>(out + ((size_t)b * NF + n) * DE);

  if (PACKED) {
    const float* wp = W + (size_t)n * DE * WREC;
    for (int d4 = 0; d4 < DE / 4; ++d4) {
      float4 o;
#pragma unroll
      for (int q = 0; q < 4; ++q) {
        const float* w = wp + (size_t)(d4 * 4 + q) * WREC;  // wave-uniform -> s_load
        float a = fmaf(sil, w[0], w[1]);
#pragma unroll
        for (int i = 0; i < NBF; ++i) a = fmaf(bs[i], w[2 + i], a);
#pragma unroll
        for (int gi = 0; gi < FG; ++gi) a = fmaf(cs[gi], w[10 + gi], a);
#pragma unroll
        for (int gi = 0; gi < FG; ++gi) a = fmaf(sn[gi], w[20 + gi], a);
        (&o.x)[q] = a;
      }
      outp[d4] = o;
    }
  } else {
    const float* bwp = bw + n * DE;
    const float* fbp = fb + n * DE;
    const float* ssp = ss + n * DE;
    const float* swp = sw + (size_t)n * DE * NBF;
    const float* f0  = fc + (size_t)n * DE * FG;
    const float* f1  = fc + (size_t)(NF + n) * DE * FG;
    for (int d4 = 0; d4 < DE / 4; ++d4) {
      float4 o;
#pragma unroll
      for (int q = 0; q < 4; ++q) {
        int d = d4 * 4 + q;
        float a = fmaf(sil, bwp[d], fbp[d]);
        float scl = ssp[d];
#pragma unroll
        for (int i = 0; i < NBF; ++i) a = fmaf(bs[i] * scl, swp[d * NBF + i], a);
#pragma unroll
        for (int gi = 0; gi < FG; ++gi) a = fmaf(cs[gi], f0[d * FG + gi], a);
#pragma unroll
        for (int gi = 0; gi < FG; ++gi) a = fmaf(sn[gi], f1[d * FG + gi], a);
        (&o.x)[q] = a;
      }
      outp[d4] = o;
    }
  }
}

extern "C" void kernel_launch(void* const* d_in, const int* in_sizes, int n_in,
                              void* d_out, int out_size, void* d_ws, size_t ws_size,
                              hipStream_t stream) {
  const float* x    = (const float*)d_in[0];
  const float* grid = (const float*)d_in[1];
  const float* bw   = (const float*)d_in[2];
  const float* sw   = (const float*)d_in[3];
  const float* ss   = (const float*)d_in[4];
  const float* fc   = (const float*)d_in[5];
  const float* fb   = (const float*)d_in[6];
  float* out = (float*)d_out;

  const int B = in_sizes[0] / NF;          // 8192
  dim3 mgrid(NF, (unsigned)((B + 255) / 256));
  const size_t need = (size_t)(NF * DE * WREC + NF * 32) * sizeof(float);

  if (ws_size >= need) {
    float* W   = (float*)d_ws;
    float* INV = W + (size_t)NF * DE * WREC;
    kan_prep<<<(NF * DE + 255) / 256, 256, 0, stream>>>(grid, bw, sw, ss, fc, fb, W, INV);
    kan_main<true><<<mgrid, 256, 0, stream>>>(x, grid, bw, sw, ss, fc, fb, W, INV, out, B);
  } else {
    kan_main<false><<<mgrid, 256, 0, stream>>>(x, grid, bw, sw, ss, fc, fb,
                                               nullptr, nullptr, out, B);
  }
}